// Round 11
// baseline (280.450 us; speedup 1.0000x reference)
//
#include <hip/hip_runtime.h>
#include <hip/hip_bf16.h>

#define NB 2
#define NL 2048
#define NH 12
#define ND 64
#define NEWTON 6
#define WV 8            // waves per block (attn)
#define TPW 16          // key-tiles per wave = 128/WV

typedef __bf16 bf16x8 __attribute__((ext_vector_type(8)));
typedef float f32x4 __attribute__((ext_vector_type(4)));
typedef float f32x2 __attribute__((ext_vector_type(2)));

// DPP row_ror reductions within each 16-lane row (all lanes end with total).
#define ROR_ADD(v, n)                                                         \
  (v) += __int_as_float(__builtin_amdgcn_update_dpp(                          \
      0, __float_as_int(v), 0x120 + (n), 0xF, 0xF, true))
#define ROR_MAX(v, n)                                                         \
  (v) = fmaxf((v), __int_as_float(__builtin_amdgcn_update_dpp(                \
                  0, __float_as_int(v), 0x120 + (n), 0xF, 0xF, true)))

__device__ __forceinline__ void split_bf16(float f, __bf16& hi, __bf16& lo) {
  __bf16 h = (__bf16)f;
  hi = h;
  lo = (__bf16)(f - (float)h);
}

// ---- prep: identical to R8-R10 (verified). 768 blocks, 256 thr, 33 KB LDS.
__global__ __launch_bounds__(256) void prep(
    const float* __restrict__ kg, const float* __restrict__ vg,
    __bf16* __restrict__ kp_hi, __bf16* __restrict__ kp_lo,
    __bf16* __restrict__ vp_hi, __bf16* __restrict__ vp_lo) {
  __shared__ __align__(16) float kv[2][16][260];
  const int blk = blockIdx.x;
  const int hg = blk % 3;
  const int kt = (blk / 3) & 127;
  const int b = blk / 384;
  const int t = threadIdx.x;
  const int w = t >> 6;
  const int lane = t & 63;
  const int quad = lane >> 4;
  const int l16 = lane & 15;

#pragma unroll
  for (int i = 0; i < 4; ++i) {
    const int f = i * 1024 + t * 4;
    const int key = f >> 8;
    const int rem = f & 255;
    const size_t src =
        (size_t)(b * NL + kt * 16 + key) * (NH * ND) + hg * 256 + rem;
    *(f32x4*)(&kv[0][key][rem]) = *(const f32x4*)(kg + src);
    *(f32x4*)(&kv[1][key][rem]) = *(const f32x4*)(vg + src);
  }
  __syncthreads();

  const int h = hg * 4 + w;

  {
    const float* p = &kv[0][l16][w * 64 + quad * 8];
    f32x4 a0 = *(const f32x4*)(p);
    f32x4 a1 = *(const f32x4*)(p + 4);
    f32x4 a2 = *(const f32x4*)(p + 32);
    f32x4 a3 = *(const f32x4*)(p + 36);
    bf16x8 h0, l0, h1, l1;
#pragma unroll
    for (int j = 0; j < 4; ++j) {
      __bf16 hb, lb;
      split_bf16(a0[j], hb, lb); h0[j] = hb;     l0[j] = lb;
      split_bf16(a1[j], hb, lb); h0[4 + j] = hb; l0[4 + j] = lb;
      split_bf16(a2[j], hb, lb); h1[j] = hb;     l1[j] = lb;
      split_bf16(a3[j], hb, lb); h1[4 + j] = hb; l1[4 + j] = lb;
    }
    const size_t basek =
        ((size_t)((b * NH + h) * 128 + kt) * 2) * 512 + lane * 8;
    *(bf16x8*)(kp_hi + basek) = h0;
    *(bf16x8*)(kp_lo + basek) = l0;
    *(bf16x8*)(kp_hi + basek + 512) = h1;
    *(bf16x8*)(kp_lo + basek + 512) = l1;
  }

  {
    const int halfsel = (kt >> 3) & 1;
    const int pi = (kt >> 4) * 8 + (kt & 7);
    const int q2 = quad & 1;
    const int nhalf = quad >> 1;
    const int qdst = 2 * halfsel + q2;
#pragma unroll
    for (int nn = 0; nn < 2; ++nn) {
      const int n = nhalf * 2 + nn;
      bf16x8 hv, lv;
#pragma unroll
      for (int j = 0; j < 8; ++j) {
        __bf16 hb, lb;
        split_bf16(kv[1][q2 * 8 + j][w * 64 + n * 16 + l16], hb, lb);
        hv[j] = hb;
        lv[j] = lb;
      }
      const size_t off =
          ((((size_t)(b * NH + h) * 64 + pi) * 4 + n) * 64 + qdst * 16 + l16) * 8;
      *(bf16x8*)(vp_hi + off) = hv;
      *(bf16x8*)(vp_lo + off) = lv;
    }
  }
}

// ---------------- main fused attention-poly kernel ----------------
// Block = 512 thr = 8 waves, owns 32 q-rows (2 MFMA q-tiles u=0,1) of one bh.
// K/V streamed ONCE per block now feed 2x the queries (halves L1/L2 bytes).
// 1 block/CU, 256-reg budget -> deep load prefetch. Scores: 128 f32/lane.
__launch_bounds__(512, 2)
__global__ void attn_poly(const float* __restrict__ qg,
                          const __bf16* __restrict__ kp_hi,
                          const __bf16* __restrict__ kp_lo,
                          const __bf16* __restrict__ vp_hi,
                          const __bf16* __restrict__ vp_lo,
                          float* __restrict__ outg) {
  // union: phase-5 weight slabs alias phase-6 exchange buffer (sequential use)
  __shared__ __align__(16) char uni[40960];
  float (*ex)[16][68] = (float(*)[16][68])uni;              // [8][16][68] 34.8KB
  __bf16 (*wslab)[2][2][16][40] = (__bf16(*)[2][2][16][40])uni;  // [w][u][buf][16][40] 40KB
  __shared__ float redmax[2][WV][17];
  __shared__ f32x2 redq[2][2][WV][17];   // [par][u][w][row]

  const int tid = threadIdx.x;
  const int w = tid >> 6;
  const int lane = tid & 63;
  const int quad = lane >> 4;
  const int l16 = lane & 15;

  const int blk = blockIdx.x;
  const int qt = blk & 63;          // 64 q-tiles of 32 rows
  const int bh = blk >> 6;
  const int h = bh % NH;
  const int b = bh / NH;
  const int qbase = qt * 32;

  // ---- Q fragments for both q-tiles: fp32 * 0.125 -> bf16 hi/lo ----
  bf16x8 qhi0[2], qlo0[2], qhi1[2], qlo1[2];
#pragma unroll
  for (int u = 0; u < 2; ++u) {
    const float* qp =
        qg + ((b * NL + qbase + u * 16 + l16) * NH + h) * ND + quad * 8;
    f32x4 a0 = *(const f32x4*)(qp);
    f32x4 a1 = *(const f32x4*)(qp + 4);
    f32x4 a2 = *(const f32x4*)(qp + 32);
    f32x4 a3 = *(const f32x4*)(qp + 36);
#pragma unroll
    for (int j = 0; j < 4; ++j) {
      __bf16 hb, lb;
      split_bf16(a0[j] * 0.125f, hb, lb); qhi0[u][j] = hb;     qlo0[u][j] = lb;
      split_bf16(a1[j] * 0.125f, hb, lb); qhi0[u][4 + j] = hb; qlo0[u][4 + j] = lb;
      split_bf16(a2[j] * 0.125f, hb, lb); qhi1[u][j] = hb;     qlo1[u][j] = lb;
      split_bf16(a3[j] * 0.125f, hb, lb); qhi1[u][4 + j] = hb; qlo1[u][4 + j] = lb;
    }
  }

  // ---- phase 1: S for both q-tiles; each K tile-load feeds 12 MFMAs ----
  f32x2 sc2[2][TPW][2];   // [u][t][j], rows quad*4+2j(+1), col l16, ktile w+8t
  {
    const __bf16* kbh = kp_hi + (size_t)bh * 131072;
    const __bf16* kbl = kp_lo + (size_t)bh * 131072;
#pragma unroll
    for (int t = 0; t < TPW; ++t) {
      const int ktile = w + WV * t;
      const size_t o = (size_t)ktile * 1024 + lane * 8;
      bf16x8 khi0 = *(const bf16x8*)(kbh + o);
      bf16x8 khi1 = *(const bf16x8*)(kbh + o + 512);
      bf16x8 klo0 = *(const bf16x8*)(kbl + o);
      bf16x8 klo1 = *(const bf16x8*)(kbl + o + 512);
#pragma unroll
      for (int u = 0; u < 2; ++u) {
        f32x4 acc = {0.f, 0.f, 0.f, 0.f};
        acc = __builtin_amdgcn_mfma_f32_16x16x32_bf16(qhi0[u], khi0, acc, 0, 0, 0);
        acc = __builtin_amdgcn_mfma_f32_16x16x32_bf16(qhi1[u], khi1, acc, 0, 0, 0);
        acc = __builtin_amdgcn_mfma_f32_16x16x32_bf16(qhi0[u], klo0, acc, 0, 0, 0);
        acc = __builtin_amdgcn_mfma_f32_16x16x32_bf16(qhi1[u], klo1, acc, 0, 0, 0);
        acc = __builtin_amdgcn_mfma_f32_16x16x32_bf16(qlo0[u], khi0, acc, 0, 0, 0);
        acc = __builtin_amdgcn_mfma_f32_16x16x32_bf16(qlo1[u], khi1, acc, 0, 0, 0);
        sc2[u][t][0] = __builtin_shufflevector(acc, acc, 0, 1);
        sc2[u][t][1] = __builtin_shufflevector(acc, acc, 2, 3);
      }
    }
  }

  // ---- phase 2: row max per q-tile -> negc[u][j] = max + 1 ----
  f32x2 negc[2][2];
  {
    f32x2 mx2[2][2];
#pragma unroll
    for (int u = 0; u < 2; ++u) {
      mx2[u][0] = sc2[u][0][0];
      mx2[u][1] = sc2[u][0][1];
#pragma unroll
      for (int t = 1; t < TPW; ++t) {
#pragma unroll
        for (int j = 0; j < 2; ++j) {
          mx2[u][j].x = fmaxf(mx2[u][j].x, sc2[u][t][j].x);
          mx2[u][j].y = fmaxf(mx2[u][j].y, sc2[u][t][j].y);
        }
      }
#pragma unroll
      for (int j = 0; j < 2; ++j) {
        ROR_MAX(mx2[u][j].x, 8); ROR_MAX(mx2[u][j].x, 4); ROR_MAX(mx2[u][j].x, 2); ROR_MAX(mx2[u][j].x, 1);
        ROR_MAX(mx2[u][j].y, 8); ROR_MAX(mx2[u][j].y, 4); ROR_MAX(mx2[u][j].y, 2); ROR_MAX(mx2[u][j].y, 1);
      }
    }
    if (l16 < 4) {
      const int r = l16;
      float v = (r == 0) ? mx2[0][0].x : (r == 1) ? mx2[0][0].y
              : (r == 2) ? mx2[0][1].x : mx2[0][1].y;
      redmax[0][w][quad * 4 + r] = v;
    } else if (l16 < 8) {
      const int r = l16 - 4;
      float v = (r == 0) ? mx2[1][0].x : (r == 1) ? mx2[1][0].y
              : (r == 2) ? mx2[1][1].x : mx2[1][1].y;
      redmax[1][w][quad * 4 + r] = v;
    }
    __syncthreads();
#pragma unroll
    for (int u = 0; u < 2; ++u) {
#pragma unroll
      for (int r = 0; r < 4; ++r) {
        float m = redmax[u][l16 & 7][quad * 4 + r];
        ROR_MAX(m, 4); ROR_MAX(m, 2); ROR_MAX(m, 1);
        ((float*)negc[u])[r] = m + 1.0f;     // -c0 = max + 1
      }
    }
  }

  // ---- phase 3: Newton x6 on c (paired rcp), one barrier per iter ----
  for (int it = 0; it < NEWTON; ++it) {
    const int par = it & 1;
    f32x2 ps2[2][2] = {{{0.f, 0.f}, {0.f, 0.f}}, {{0.f, 0.f}, {0.f, 0.f}}};
    f32x2 psd2[2][2] = {{{0.f, 0.f}, {0.f, 0.f}}, {{0.f, 0.f}, {0.f, 0.f}}};
#pragma unroll
    for (int t = 0; t < TPW; ++t) {
#pragma unroll
      for (int u = 0; u < 2; ++u) {
#pragma unroll
        for (int j = 0; j < 2; ++j) {
          f32x2 y = negc[u][j] - sc2[u][t][j];
          float z = __builtin_amdgcn_rcpf(y.x * y.y);
          f32x2 r1 = z * __builtin_shufflevector(y, y, 1, 0);
          f32x2 r2 = r1 * r1;
          ps2[u][j] += r2;
          psd2[u][j] += r2 * r1;
        }
      }
    }
#pragma unroll
    for (int u = 0; u < 2; ++u) {
#pragma unroll
      for (int j = 0; j < 2; ++j) {
        ROR_ADD(ps2[u][j].x, 8);  ROR_ADD(ps2[u][j].x, 4);  ROR_ADD(ps2[u][j].x, 2);  ROR_ADD(ps2[u][j].x, 1);
        ROR_ADD(ps2[u][j].y, 8);  ROR_ADD(ps2[u][j].y, 4);  ROR_ADD(ps2[u][j].y, 2);  ROR_ADD(ps2[u][j].y, 1);
        ROR_ADD(psd2[u][j].x, 8); ROR_ADD(psd2[u][j].x, 4); ROR_ADD(psd2[u][j].x, 2); ROR_ADD(psd2[u][j].x, 1);
        ROR_ADD(psd2[u][j].y, 8); ROR_ADD(psd2[u][j].y, 4); ROR_ADD(psd2[u][j].y, 2); ROR_ADD(psd2[u][j].y, 1);
      }
    }
    if (l16 < 4) {
      const int r = l16;
      float a = (r == 0) ? ps2[0][0].x : (r == 1) ? ps2[0][0].y
              : (r == 2) ? ps2[0][1].x : ps2[0][1].y;
      float d = (r == 0) ? psd2[0][0].x : (r == 1) ? psd2[0][0].y
              : (r == 2) ? psd2[0][1].x : psd2[0][1].y;
      redq[par][0][w][quad * 4 + r] = f32x2{a, d};
    } else if (l16 < 8) {
      const int r = l16 - 4;
      float a = (r == 0) ? ps2[1][0].x : (r == 1) ? ps2[1][0].y
              : (r == 2) ? ps2[1][1].x : ps2[1][1].y;
      float d = (r == 0) ? psd2[1][0].x : (r == 1) ? psd2[1][0].y
              : (r == 2) ? psd2[1][1].x : psd2[1][1].y;
      redq[par][1][w][quad * 4 + r] = f32x2{a, d};
    }
    __syncthreads();
#pragma unroll
    for (int u = 0; u < 2; ++u) {
#pragma unroll
      for (int r = 0; r < 4; ++r) {
        f32x2 v = redq[par][u][l16 & 7][quad * 4 + r];
        ROR_ADD(v.x, 4); ROR_ADD(v.x, 2); ROR_ADD(v.x, 1);
        ROR_ADD(v.y, 4); ROR_ADD(v.y, 2); ROR_ADD(v.y, 1);
        ((float*)negc[u])[r] +=
            (v.x - 1.0f) * __builtin_amdgcn_rcpf(2.0f * v.y + 1e-8f);
      }
    }
  }

  // ---- phase 5: O = W * (Vhi + Vlo); dbuf bf16 slabs; V feeds both q-tiles ----
  f32x4 oacc[2][4];
#pragma unroll
  for (int u = 0; u < 2; ++u)
#pragma unroll
    for (int n = 0; n < 4; ++n) oacc[u][n] = (f32x4){0.f, 0.f, 0.f, 0.f};
  const __bf16* vpbh = vp_hi + (size_t)bh * 131072;
  const __bf16* vpbl = vp_lo + (size_t)bh * 131072;

  // prologue: weights for tiles 0,1 (both q-tiles) -> buf 0
#pragma unroll
  for (int u = 0; u < 2; ++u) {
#pragma unroll
    for (int ts = 0; ts < 2; ++ts) {
      f32x2 a = negc[u][0] - sc2[u][ts][0];
      f32x2 bb = negc[u][1] - sc2[u][ts][1];
      float za = __builtin_amdgcn_rcpf(a.x * a.y);
      float zb = __builtin_amdgcn_rcpf(bb.x * bb.y);
      f32x2 ra = za * __builtin_shufflevector(a, a, 1, 0);
      f32x2 rb = zb * __builtin_shufflevector(bb, bb, 1, 0);
      f32x2 wa = ra * ra;
      f32x2 wb = rb * rb;
      wslab[w][u][0][quad * 4 + 0][ts * 16 + l16] = (__bf16)wa.x;
      wslab[w][u][0][quad * 4 + 1][ts * 16 + l16] = (__bf16)wa.y;
      wslab[w][u][0][quad * 4 + 2][ts * 16 + l16] = (__bf16)wb.x;
      wslab[w][u][0][quad * 4 + 3][ts * 16 + l16] = (__bf16)wb.y;
    }
  }

#pragma unroll
  for (int p = 0; p < 8; ++p) {
    const size_t vo = ((size_t)(p * 8 + w) * 4) * 512 + lane * 8;
    bf16x8 bhv0 = *(const bf16x8*)(vpbh + vo);
    bf16x8 bhv1 = *(const bf16x8*)(vpbh + vo + 512);
    bf16x8 bhv2 = *(const bf16x8*)(vpbh + vo + 1024);
    bf16x8 bhv3 = *(const bf16x8*)(vpbh + vo + 1536);
    bf16x8 blv0 = *(const bf16x8*)(vpbl + vo);
    bf16x8 blv1 = *(const bf16x8*)(vpbl + vo + 512);
    bf16x8 blv2 = *(const bf16x8*)(vpbl + vo + 1024);
    bf16x8 blv3 = *(const bf16x8*)(vpbl + vo + 1536);

    asm volatile("s_waitcnt lgkmcnt(0)" ::: "memory");  // slab writes visible
    bf16x8 awA = *(const bf16x8*)(&wslab[w][0][p & 1][l16][quad * 8]);
    bf16x8 awB = *(const bf16x8*)(&wslab[w][1][p & 1][l16][quad * 8]);

    if (p < 7) {
#pragma unroll
      for (int u = 0; u < 2; ++u) {
#pragma unroll
        for (int ts = 0; ts < 2; ++ts) {
          const int t = 2 * (p + 1) + ts;
          f32x2 a = negc[u][0] - sc2[u][t][0];
          f32x2 bb = negc[u][1] - sc2[u][t][1];
          float za = __builtin_amdgcn_rcpf(a.x * a.y);
          float zb = __builtin_amdgcn_rcpf(bb.x * bb.y);
          f32x2 ra = za * __builtin_shufflevector(a, a, 1, 0);
          f32x2 rb = zb * __builtin_shufflevector(bb, bb, 1, 0);
          f32x2 wa = ra * ra;
          f32x2 wb = rb * rb;
          wslab[w][u][(p + 1) & 1][quad * 4 + 0][ts * 16 + l16] = (__bf16)wa.x;
          wslab[w][u][(p + 1) & 1][quad * 4 + 1][ts * 16 + l16] = (__bf16)wa.y;
          wslab[w][u][(p + 1) & 1][quad * 4 + 2][ts * 16 + l16] = (__bf16)wb.x;
          wslab[w][u][(p + 1) & 1][quad * 4 + 3][ts * 16 + l16] = (__bf16)wb.y;
        }
      }
    }

    oacc[0][0] = __builtin_amdgcn_mfma_f32_16x16x32_bf16(awA, bhv0, oacc[0][0], 0, 0, 0);
    oacc[0][1] = __builtin_amdgcn_mfma_f32_16x16x32_bf16(awA, bhv1, oacc[0][1], 0, 0, 0);
    oacc[0][2] = __builtin_amdgcn_mfma_f32_16x16x32_bf16(awA, bhv2, oacc[0][2], 0, 0, 0);
    oacc[0][3] = __builtin_amdgcn_mfma_f32_16x16x32_bf16(awA, bhv3, oacc[0][3], 0, 0, 0);
    oacc[1][0] = __builtin_amdgcn_mfma_f32_16x16x32_bf16(awB, bhv0, oacc[1][0], 0, 0, 0);
    oacc[1][1] = __builtin_amdgcn_mfma_f32_16x16x32_bf16(awB, bhv1, oacc[1][1], 0, 0, 0);
    oacc[1][2] = __builtin_amdgcn_mfma_f32_16x16x32_bf16(awB, bhv2, oacc[1][2], 0, 0, 0);
    oacc[1][3] = __builtin_amdgcn_mfma_f32_16x16x32_bf16(awB, bhv3, oacc[1][3], 0, 0, 0);
    oacc[0][0] = __builtin_amdgcn_mfma_f32_16x16x32_bf16(awA, blv0, oacc[0][0], 0, 0, 0);
    oacc[0][1] = __builtin_amdgcn_mfma_f32_16x16x32_bf16(awA, blv1, oacc[0][1], 0, 0, 0);
    oacc[0][2] = __builtin_amdgcn_mfma_f32_16x16x32_bf16(awA, blv2, oacc[0][2], 0, 0, 0);
    oacc[0][3] = __builtin_amdgcn_mfma_f32_16x16x32_bf16(awA, blv3, oacc[0][3], 0, 0, 0);
    oacc[1][0] = __builtin_amdgcn_mfma_f32_16x16x32_bf16(awB, blv0, oacc[1][0], 0, 0, 0);
    oacc[1][1] = __builtin_amdgcn_mfma_f32_16x16x32_bf16(awB, blv1, oacc[1][1], 0, 0, 0);
    oacc[1][2] = __builtin_amdgcn_mfma_f32_16x16x32_bf16(awB, blv2, oacc[1][2], 0, 0, 0);
    oacc[1][3] = __builtin_amdgcn_mfma_f32_16x16x32_bf16(awB, blv3, oacc[1][3], 0, 0, 0);
  }

  // ---- phase 6: per q-tile, reduce partials across waves, write global ----
  __syncthreads();  // all phase-5 slab reads done before ex (aliased) writes
#pragma unroll
  for (int u = 0; u < 2; ++u) {
#pragma unroll
    for (int n = 0; n < 4; ++n)
#pragma unroll
      for (int r = 0; r < 4; ++r)
        ex[w][quad * 4 + r][n * 16 + l16] = oacc[u][n][r];
    __syncthreads();
    {
      const int row = 2 * w + (lane >> 5);
      const int d = lane & 31;
      float v0 = 0.f, v1 = 0.f;
#pragma unroll
      for (int i = 0; i < WV; ++i) {
        v0 += ex[i][row][d];
        v1 += ex[i][row][d + 32];
      }
      const int off = ((b * NL + qbase + u * 16 + row) * NH + h) * ND + d;
      outg[off] = v0;
      outg[off + 32] = v1;
    }
    if (u == 0) __syncthreads();  // protect ex before overwrite with u=1
  }
}

extern "C" void kernel_launch(void* const* d_in, const int* in_sizes, int n_in,
                              void* d_out, int out_size, void* d_ws, size_t ws_size,
                              hipStream_t stream) {
  const float* q = (const float*)d_in[0];
  const float* k = (const float*)d_in[1];
  const float* v = (const float*)d_in[2];

  const size_t plane = (size_t)NB * NH * ND * NL;  // 3.15M elems, 6.29MB/plane
  __bf16* kp_hi = (__bf16*)d_ws;
  __bf16* kp_lo = kp_hi + plane;
  __bf16* vp_hi = kp_lo + plane;
  __bf16* vp_lo = vp_hi + plane;

  prep<<<NB * 128 * 3, 256, 0, stream>>>(k, v, kp_hi, kp_lo, vp_hi, vp_lo);

  attn_poly<<<NB * NH * (NL / 32), 512, 0, stream>>>(
      q, kp_hi, kp_lo, vp_hi, vp_lo, (float*)d_out);
}